// Round 3
// baseline (778.469 us; speedup 1.0000x reference)
//
#include <hip/hip_runtime.h>
#include <hip/hip_bf16.h>

// Problem constants
constexpr int kD  = 768;
constexpr int kH  = 12;
constexpr int kDH = 64;
constexpr int kS  = 1500;
constexpr int kSP = 1504;        // S padded to multiple of 32 (47*32)
constexpr int kB  = 8;
constexpr int kM  = kB * kS;     // 12000 rows for the projections
constexpr float kScale = 0.125f;

typedef __bf16 bf16;
typedef __bf16 bf16x8 __attribute__((ext_vector_type(8)));
typedef float  floatx4 __attribute__((ext_vector_type(4)));

// ---------------------------------------------------------------------------
// Dtype probe: read x as bf16 at even indices. If data is really f32, the even
// bf16 slots are float mantissa halves -> uniform-ish bit patterns -> many
// NaN/Inf/huge/denormal values. Sane bf16 N(0,1) data has none.
// (Round-1 NaN already proved f32; keep the probe as a cheap guard.)
// ---------------------------------------------------------------------------
__global__ __launch_bounds__(256) void detect_kernel(const void* __restrict__ xraw,
                                                     int* __restrict__ flag) {
    __shared__ int bad;
    if (threadIdx.x == 0) bad = 0;
    __syncthreads();
    const bf16* xb = (const bf16*)xraw;
    int c = 0;
    for (int k = 0; k < 16; k++) {
        int idx = 2 * (threadIdx.x + 256 * k);   // even indices 0..8190
        float v = fabsf((float)xb[idx]);
        if (!(v == 0.0f || (v > 1e-20f && v < 1e6f))) c++;
    }
    atomicAdd(&bad, c);
    __syncthreads();
    if (threadIdx.x == 0) *flag = (bad > 8) ? 1 : 0;   // 1 => source is float32
}

__global__ __launch_bounds__(256) void cvt_bf16_kernel(const void* __restrict__ src,
                                                       bf16* __restrict__ dst, int n,
                                                       const int* __restrict__ flag) {
    int i = blockIdx.x * 256 + threadIdx.x;
    if (i < n) {
        if (*flag)
            dst[i] = (bf16)((const float*)src)[i];
        else
            dst[i] = ((const bf16*)src)[i];
    }
}

__global__ __launch_bounds__(256) void cvt_f32_kernel(const void* __restrict__ src,
                                                      float* __restrict__ dst, int n,
                                                      const int* __restrict__ flag) {
    int i = blockIdx.x * 256 + threadIdx.x;
    if (i < n) {
        if (*flag)
            dst[i] = ((const float*)src)[i];
        else
            dst[i] = (float)((const bf16*)src)[i];
    }
}

// ---------------------------------------------------------------------------
// Zero the S-padding rows of q/k (layout [B*H][Sp][DH]) and padding cols of
// v^T (layout [B*H][DH][Sp]) so padded keys/queries are inert.
// ---------------------------------------------------------------------------
__global__ __launch_bounds__(256) void zeropad_kernel(bf16* __restrict__ q_ws,
                                                      bf16* __restrict__ k_ws,
                                                      bf16* __restrict__ vt_ws) {
    int t = blockIdx.x * 256 + threadIdx.x;          // 96 bh * 4 s * 64 dh = 24576
    if (t < kB * kH * (kSP - kS) * kDH) {
        int bh  = t >> 8;
        int rem = t & 255;
        int s   = kS + (rem >> 6);
        int dh  = rem & 63;
        size_t qi = ((size_t)bh * kSP + s) * kDH + dh;
        q_ws[qi] = (bf16)0.f;
        k_ws[qi] = (bf16)0.f;
        size_t vi = ((size_t)bh * kDH + dh) * kSP + s;
        vt_ws[vi] = (bf16)0.f;
    }
}

// ---------------------------------------------------------------------------
// Tiled MFMA GEMM: out = X[M x 768] @ W^T[768 x 768] (+bias)(*scale)
// 64x64 tile / block, 4 waves, each wave a 32x32 quadrant (2x2 MFMA tiles).
// MODE 0: Q  -> bf16 [B,H,Sp,DH], (acc+bq)*0.125
// MODE 1: K  -> bf16 [B,H,Sp,DH], no bias
// MODE 2: V  -> bf16 [B,H,DH,Sp] (transposed), acc+bv
// MODE 3: O  -> FLOAT32 [M, 768] (d_out),      acc+bo
// ---------------------------------------------------------------------------
template <int MODE>
__global__ __launch_bounds__(256) void proj_kernel(const bf16* __restrict__ X,
                                                   const bf16* __restrict__ W,
                                                   const float* __restrict__ bias,
                                                   bf16* __restrict__ out,
                                                   float* __restrict__ outf) {
    __shared__ bf16 Asm[64][40];   // +8 bf16 pad: row stride 80B (16B aligned)
    __shared__ bf16 Bsm[64][40];

    const int tid  = threadIdx.x;
    const int m0   = blockIdx.x * 64;
    const int n0   = blockIdx.y * 64;
    const int lane = tid & 63;
    const int w    = tid >> 6;
    const int wm   = (w >> 1) * 32;
    const int wn   = (w & 1) * 32;
    const int lrow = lane & 15;     // fragment row (m or n)
    const int lq   = lane >> 4;     // quad: k-offset = lq*8

    const int ldrow = tid >> 2;         // 0..63
    const int ldcol = (tid & 3) * 8;    // 0,8,16,24
    const int gm    = m0 + ldrow;

    floatx4 acc[2][2] = {};

    for (int k0 = 0; k0 < kD; k0 += 32) {
        bf16x8 av = {};
        if (gm < kM)
            av = *(const bf16x8*)(X + (size_t)gm * kD + k0 + ldcol);
        *(bf16x8*)(&Asm[ldrow][ldcol]) = av;
        bf16x8 bv8 = *(const bf16x8*)(W + (size_t)(n0 + ldrow) * kD + k0 + ldcol);
        *(bf16x8*)(&Bsm[ldrow][ldcol]) = bv8;
        __syncthreads();

        bf16x8 af[2], bfr[2];
#pragma unroll
        for (int i = 0; i < 2; i++)
            af[i] = *(const bf16x8*)(&Asm[wm + i * 16 + lrow][lq * 8]);
#pragma unroll
        for (int j = 0; j < 2; j++)
            bfr[j] = *(const bf16x8*)(&Bsm[wn + j * 16 + lrow][lq * 8]);
#pragma unroll
        for (int i = 0; i < 2; i++)
#pragma unroll
            for (int j = 0; j < 2; j++)
                acc[i][j] = __builtin_amdgcn_mfma_f32_16x16x32_bf16(
                    af[i], bfr[j], acc[i][j], 0, 0, 0);
        __syncthreads();
    }

    // Epilogue
#pragma unroll
    for (int i = 0; i < 2; i++) {
#pragma unroll
        for (int j = 0; j < 2; j++) {
            const int n = n0 + wn + j * 16 + lrow;
            const float bval = (MODE == 1) ? 0.f : bias[n];
#pragma unroll
            for (int r = 0; r < 4; r++) {
                const int m = m0 + wm + i * 16 + lq * 4 + r;
                if (m >= kM) continue;
                float v = acc[i][j][r];
                if (MODE == 0)      v = (v + bval) * kScale;
                else if (MODE != 1) v = v + bval;
                if (MODE == 3) {
                    outf[(size_t)m * kD + n] = v;          // float32 output!
                } else {
                    const int bb = m / kS, s = m - bb * kS;
                    const int hh = n >> 6, dh = n & 63;
                    if (MODE == 2)
                        out[(((size_t)(bb * kH + hh)) * kDH + dh) * kSP + s] = (bf16)v;
                    else
                        out[(((size_t)(bb * kH + hh)) * kSP + s) * kDH + dh] = (bf16)v;
                }
            }
        }
    }
}

// ---------------------------------------------------------------------------
// Attention core: one block = one (b,h, 16-row Q tile). 4 waves.
// Phase 1: scores (QK^T) into bf16 LDS strip [16][1512].
// Phase 2: two-pass softmax (shfl reductions over 16 threads/row),
//          exp stored unnormalized; 1/sum applied in PV epilogue.
// Phase 3: PV, wave w owns DH chunk [16w,16w+16); writes ctx [B*S][768] bf16.
// ---------------------------------------------------------------------------
__global__ __launch_bounds__(256) void attn_kernel(const bf16* __restrict__ q_ws,
                                                   const bf16* __restrict__ k_ws,
                                                   const bf16* __restrict__ vt_ws,
                                                   bf16* __restrict__ ctx) {
    constexpr int STRIDE = 1512;   // bf16; row stride 3024B: 16B aligned
    __shared__ bf16  strip[16 * STRIDE];
    __shared__ float rowrnorm[16];

    const int qt = blockIdx.x;          // 0..93
    const int bh = blockIdx.y;          // 0..95
    const int b  = bh / kH;
    const int h  = bh - b * kH;
    const int q0 = qt * 16;

    const int tid  = threadIdx.x;
    const int w    = tid >> 6;
    const int lane = tid & 63;
    const int lrow = lane & 15;
    const int lq   = lane >> 4;

    const bf16* qbase = q_ws  + (size_t)bh * kSP * kDH;
    const bf16* kbase = k_ws  + (size_t)bh * kSP * kDH;
    const bf16* vbase = vt_ws + (size_t)bh * kDH * kSP;

    // Q fragments for this tile (reused across all key tiles)
    const bf16x8 qf0 = *(const bf16x8*)(qbase + (size_t)(q0 + lrow) * kDH + lq * 8);
    const bf16x8 qf1 = *(const bf16x8*)(qbase + (size_t)(q0 + lrow) * kDH + 32 + lq * 8);

    // ---- Phase 1: scores ----
    for (int kt = w; kt < kSP / 16; kt += 4) {
        const int s0 = kt * 16;
        const bf16x8 kf0 = *(const bf16x8*)(kbase + (size_t)(s0 + lrow) * kDH + lq * 8);
        const bf16x8 kf1 = *(const bf16x8*)(kbase + (size_t)(s0 + lrow) * kDH + 32 + lq * 8);
        floatx4 sc = {};
        sc = __builtin_amdgcn_mfma_f32_16x16x32_bf16(qf0, kf0, sc, 0, 0, 0);
        sc = __builtin_amdgcn_mfma_f32_16x16x32_bf16(qf1, kf1, sc, 0, 0, 0);
#pragma unroll
        for (int r = 0; r < 4; r++)
            strip[(lq * 4 + r) * STRIDE + s0 + lrow] = (bf16)sc[r];
    }
    __syncthreads();

    // ---- Phase 2: softmax (16 threads per row) ----
    {
        const int r = tid >> 4;
        const int c = tid & 15;
        float mx = -1e30f;
        for (int col = c; col < kS; col += 16)
            mx = fmaxf(mx, (float)strip[r * STRIDE + col]);
#pragma unroll
        for (int m = 8; m >= 1; m >>= 1)
            mx = fmaxf(mx, __shfl_xor(mx, m, 16));
        float sum = 0.f;
        for (int col = c; col < kSP; col += 16) {
            float e = 0.f;
            if (col < kS)
                e = __expf((float)strip[r * STRIDE + col] - mx);
            strip[r * STRIDE + col] = (bf16)e;
            sum += e;
        }
#pragma unroll
        for (int m = 8; m >= 1; m >>= 1)
            sum += __shfl_xor(sum, m, 16);
        if (c == 0) rowrnorm[r] = 1.0f / sum;
    }
    __syncthreads();

    // ---- Phase 3: PV (wave w -> DH chunk w) ----
    floatx4 acc = {};
    const bf16* vb = vbase + (size_t)(w * 16 + lrow) * kSP;
    for (int kc = 0; kc < kSP / 32; kc++) {
        const bf16x8 pf = *(const bf16x8*)(&strip[lrow * STRIDE + kc * 32 + lq * 8]);
        const bf16x8 vf = *(const bf16x8*)(vb + kc * 32 + lq * 8);
        acc = __builtin_amdgcn_mfma_f32_16x16x32_bf16(pf, vf, acc, 0, 0, 0);
    }
#pragma unroll
    for (int r = 0; r < 4; r++) {
        const int qrow = lq * 4 + r;
        const int q = q0 + qrow;
        if (q < kS) {
            const float v = acc[r] * rowrnorm[qrow];
            ctx[((size_t)(b * kS + q)) * kD + h * kDH + w * 16 + lrow] = (bf16)v;
        }
    }
}

// ---------------------------------------------------------------------------
extern "C" void kernel_launch(void* const* d_in, const int* in_sizes, int n_in,
                              void* d_out, int out_size, void* d_ws, size_t ws_size,
                              hipStream_t stream) {
    float* out_f = (float*)d_out;   // reference output dtype is float32

    constexpr size_t nX = (size_t)kM * kD;            // 9,216,000
    constexpr size_t nW = (size_t)kD * kD;            // 589,824
    constexpr size_t per_qkv = (size_t)kB * kH * kSP * kDH;   // 9,240,576

    bf16* xb    = (bf16*)d_ws;         // also reused as ctx after last read
    bf16* Wqb   = xb + nX;
    bf16* Wkb   = Wqb + nW;
    bf16* Wvb   = Wkb + nW;
    bf16* Wob   = Wvb + nW;
    bf16* q_ws  = Wob + nW;
    bf16* k_ws  = q_ws + per_qkv;
    bf16* vt_ws = k_ws + per_qkv;
    float* bqf  = (float*)(vt_ws + per_qkv);
    float* bvf  = bqf + kD;
    float* bof  = bvf + kD;
    int*  flag  = (int*)(bof + kD);
    bf16* ctx   = xb;   // alias: xb last read by proj<2>, ctx written after

    // 1) dtype probe + input normalization to bf16 (biases to f32)
    detect_kernel<<<1, 256, 0, stream>>>(d_in[0], flag);
    cvt_bf16_kernel<<<(int)((nX + 255) / 256), 256, 0, stream>>>(d_in[0], xb,  (int)nX, flag);
    cvt_bf16_kernel<<<(int)((nW + 255) / 256), 256, 0, stream>>>(d_in[1], Wqb, (int)nW, flag);
    cvt_bf16_kernel<<<(int)((nW + 255) / 256), 256, 0, stream>>>(d_in[3], Wkb, (int)nW, flag);
    cvt_bf16_kernel<<<(int)((nW + 255) / 256), 256, 0, stream>>>(d_in[4], Wvb, (int)nW, flag);
    cvt_bf16_kernel<<<(int)((nW + 255) / 256), 256, 0, stream>>>(d_in[6], Wob, (int)nW, flag);
    cvt_f32_kernel<<<3, 256, 0, stream>>>(d_in[2], bqf, kD, flag);
    cvt_f32_kernel<<<3, 256, 0, stream>>>(d_in[5], bvf, kD, flag);
    cvt_f32_kernel<<<3, 256, 0, stream>>>(d_in[7], bof, kD, flag);

    // 2) QKV projections (+ padding)
    zeropad_kernel<<<96, 256, 0, stream>>>(q_ws, k_ws, vt_ws);
    dim3 pgrid((kM + 63) / 64, kD / 64);   // 188 x 12
    proj_kernel<0><<<pgrid, 256, 0, stream>>>(xb, Wqb, bqf, q_ws, nullptr);
    proj_kernel<1><<<pgrid, 256, 0, stream>>>(xb, Wkb, nullptr, k_ws, nullptr);
    proj_kernel<2><<<pgrid, 256, 0, stream>>>(xb, Wvb, bvf, vt_ws, nullptr);

    // 3) attention
    attn_kernel<<<dim3(kSP / 16, kB * kH), 256, 0, stream>>>(q_ws, k_ws, vt_ws, ctx);

    // 4) output projection -> float32 d_out
    proj_kernel<3><<<pgrid, 256, 0, stream>>>(ctx, Wob, bof, nullptr, out_f);
}

// Round 4
// 604.799 us; speedup vs baseline: 1.2872x; 1.2872x over previous
//
#include <hip/hip_runtime.h>
#include <hip/hip_bf16.h>

// Problem constants
constexpr int kD  = 768;
constexpr int kH  = 12;
constexpr int kDH = 64;
constexpr int kS  = 1500;
constexpr int kSP = 1504;        // S padded to multiple of 32 (47*32)
constexpr int kB  = 8;
constexpr int kM  = kB * kS;     // 12000 rows for the projections
constexpr float kScale = 0.125f;
constexpr int kPSTR = 72;        // P-buffer row stride (elems): 144B = 16B-aligned

typedef __bf16 bf16;
typedef __bf16 bf16x8 __attribute__((ext_vector_type(8)));
typedef float  floatx4 __attribute__((ext_vector_type(4)));

// ---------------------------------------------------------------------------
// Dtype probe (round-1 NaN proved inputs are f32; cheap guard retained).
// ---------------------------------------------------------------------------
__global__ __launch_bounds__(256) void detect_kernel(const void* __restrict__ xraw,
                                                     int* __restrict__ flag) {
    __shared__ int bad;
    if (threadIdx.x == 0) bad = 0;
    __syncthreads();
    const bf16* xb = (const bf16*)xraw;
    int c = 0;
    for (int k = 0; k < 16; k++) {
        int idx = 2 * (threadIdx.x + 256 * k);
        float v = fabsf((float)xb[idx]);
        if (!(v == 0.0f || (v > 1e-20f && v < 1e6f))) c++;
    }
    atomicAdd(&bad, c);
    __syncthreads();
    if (threadIdx.x == 0) *flag = (bad > 8) ? 1 : 0;
}

__global__ __launch_bounds__(256) void cvt_bf16_kernel(const void* __restrict__ src,
                                                       bf16* __restrict__ dst, int n,
                                                       const int* __restrict__ flag) {
    int i = blockIdx.x * 256 + threadIdx.x;
    if (i < n) {
        if (*flag)
            dst[i] = (bf16)((const float*)src)[i];
        else
            dst[i] = ((const bf16*)src)[i];
    }
}

__global__ __launch_bounds__(256) void cvt_f32_kernel(const void* __restrict__ src,
                                                      float* __restrict__ dst, int n,
                                                      const int* __restrict__ flag) {
    int i = blockIdx.x * 256 + threadIdx.x;
    if (i < n) {
        if (*flag)
            dst[i] = ((const float*)src)[i];
        else
            dst[i] = (float)((const bf16*)src)[i];
    }
}

// ---------------------------------------------------------------------------
// Zero the S-padding rows of q/k and padding cols of v^T.
// ---------------------------------------------------------------------------
__global__ __launch_bounds__(256) void zeropad_kernel(bf16* __restrict__ q_ws,
                                                      bf16* __restrict__ k_ws,
                                                      bf16* __restrict__ vt_ws) {
    int t = blockIdx.x * 256 + threadIdx.x;          // 96 bh * 4 s * 64 dh = 24576
    if (t < kB * kH * (kSP - kS) * kDH) {
        int bh  = t >> 8;
        int rem = t & 255;
        int s   = kS + (rem >> 6);
        int dh  = rem & 63;
        size_t qi = ((size_t)bh * kSP + s) * kDH + dh;
        q_ws[qi] = (bf16)0.f;
        k_ws[qi] = (bf16)0.f;
        size_t vi = ((size_t)bh * kDH + dh) * kSP + s;
        vt_ws[vi] = (bf16)0.f;
    }
}

// ---------------------------------------------------------------------------
// Tiled MFMA GEMM (unchanged from passing round 3).
// MODE 0: Q -> bf16 [B,H,Sp,DH], (acc+bq)*0.125
// MODE 1: K -> bf16 [B,H,Sp,DH]
// MODE 2: V -> bf16 [B,H,DH,Sp] (transposed), acc+bv
// MODE 3: O -> f32 [M,768] (d_out), acc+bo
// ---------------------------------------------------------------------------
template <int MODE>
__global__ __launch_bounds__(256) void proj_kernel(const bf16* __restrict__ X,
                                                   const bf16* __restrict__ W,
                                                   const float* __restrict__ bias,
                                                   bf16* __restrict__ out,
                                                   float* __restrict__ outf) {
    __shared__ bf16 Asm[64][40];
    __shared__ bf16 Bsm[64][40];

    const int tid  = threadIdx.x;
    const int m0   = blockIdx.x * 64;
    const int n0   = blockIdx.y * 64;
    const int lane = tid & 63;
    const int w    = tid >> 6;
    const int wm   = (w >> 1) * 32;
    const int wn   = (w & 1) * 32;
    const int lrow = lane & 15;
    const int lq   = lane >> 4;

    const int ldrow = tid >> 2;
    const int ldcol = (tid & 3) * 8;
    const int gm    = m0 + ldrow;

    floatx4 acc[2][2] = {};

    for (int k0 = 0; k0 < kD; k0 += 32) {
        bf16x8 av = {};
        if (gm < kM)
            av = *(const bf16x8*)(X + (size_t)gm * kD + k0 + ldcol);
        *(bf16x8*)(&Asm[ldrow][ldcol]) = av;
        bf16x8 bv8 = *(const bf16x8*)(W + (size_t)(n0 + ldrow) * kD + k0 + ldcol);
        *(bf16x8*)(&Bsm[ldrow][ldcol]) = bv8;
        __syncthreads();

        bf16x8 af[2], bfr[2];
#pragma unroll
        for (int i = 0; i < 2; i++)
            af[i] = *(const bf16x8*)(&Asm[wm + i * 16 + lrow][lq * 8]);
#pragma unroll
        for (int j = 0; j < 2; j++)
            bfr[j] = *(const bf16x8*)(&Bsm[wn + j * 16 + lrow][lq * 8]);
#pragma unroll
        for (int i = 0; i < 2; i++)
#pragma unroll
            for (int j = 0; j < 2; j++)
                acc[i][j] = __builtin_amdgcn_mfma_f32_16x16x32_bf16(
                    af[i], bfr[j], acc[i][j], 0, 0, 0);
        __syncthreads();
    }

#pragma unroll
    for (int i = 0; i < 2; i++) {
#pragma unroll
        for (int j = 0; j < 2; j++) {
            const int n = n0 + wn + j * 16 + lrow;
            const float bval = (MODE == 1) ? 0.f : bias[n];
#pragma unroll
            for (int r = 0; r < 4; r++) {
                const int m = m0 + wm + i * 16 + lq * 4 + r;
                if (m >= kM) continue;
                float v = acc[i][j][r];
                if (MODE == 0)      v = (v + bval) * kScale;
                else if (MODE != 1) v = v + bval;
                if (MODE == 3) {
                    outf[(size_t)m * kD + n] = v;
                } else {
                    const int bb = m / kS, s = m - bb * kS;
                    const int hh = n >> 6, dh = n & 63;
                    if (MODE == 2)
                        out[(((size_t)(bb * kH + hh)) * kDH + dh) * kSP + s] = (bf16)v;
                    else
                        out[(((size_t)(bb * kH + hh)) * kSP + s) * kDH + dh] = (bf16)v;
                }
            }
        }
    }
}

// ---------------------------------------------------------------------------
// Flash attention: one block = (b,h, 64 Q rows); each of 4 waves owns 16 Q
// rows and runs fully independently (no __syncthreads). Online softmax in
// registers; P transposes C->A layout through a 2.3KB per-wave LDS buffer.
// NT = number of 16-key subtiles in the chunk (4 = 64 keys, 2 = 32-key tail).
// ---------------------------------------------------------------------------
template <int NT, bool MASK>
__device__ __forceinline__ void attn_chunk(int s0,
                                           const bf16* __restrict__ kbase,
                                           const bf16* __restrict__ vbase,
                                           bf16* __restrict__ P,
                                           const bf16x8 qf[2],
                                           float m_i[4], float l_i[4],
                                           floatx4 Oacc[4],
                                           int col, int quad) {
    floatx4 sc[NT];
#pragma unroll
    for (int t = 0; t < NT; t++) {
        sc[t] = (floatx4){0.f, 0.f, 0.f, 0.f};
        const bf16* kr = kbase + (size_t)(s0 + 16 * t + col) * kDH + quad * 8;
        const bf16x8 kf0 = *(const bf16x8*)(kr);
        const bf16x8 kf1 = *(const bf16x8*)(kr + 32);
        sc[t] = __builtin_amdgcn_mfma_f32_16x16x32_bf16(qf[0], kf0, sc[t], 0, 0, 0);
        sc[t] = __builtin_amdgcn_mfma_f32_16x16x32_bf16(qf[1], kf1, sc[t], 0, 0, 0);
    }
    if (MASK) {
#pragma unroll
        for (int t = 0; t < NT; t++)
            if (s0 + 16 * t + col >= kS)
                sc[t] = (floatx4){-1e30f, -1e30f, -1e30f, -1e30f};
    }
    // chunk row max (rows = quad*4+r; reduce across the 16 col-lanes)
    float cm[4], alpha[4], rs[4];
#pragma unroll
    for (int r = 0; r < 4; r++) {
        float v = sc[0][r];
#pragma unroll
        for (int t = 1; t < NT; t++) v = fmaxf(v, sc[t][r]);
        cm[r] = v;
    }
#pragma unroll
    for (int off = 1; off < 16; off <<= 1)
#pragma unroll
        for (int r = 0; r < 4; r++)
            cm[r] = fmaxf(cm[r], __shfl_xor(cm[r], off, 16));
#pragma unroll
    for (int r = 0; r < 4; r++) {
        const float mn = fmaxf(m_i[r], cm[r]);
        alpha[r] = __expf(m_i[r] - mn);
        m_i[r]   = mn;
        rs[r]    = 0.f;
    }
    // p = exp(sc - m), row-sum, stash bf16 P in [row][key] LDS
#pragma unroll
    for (int t = 0; t < NT; t++)
#pragma unroll
        for (int r = 0; r < 4; r++) {
            const float p = __expf(sc[t][r] - m_i[r]);
            rs[r] += p;
            P[(quad * 4 + r) * kPSTR + 16 * t + col] = (bf16)p;
        }
#pragma unroll
    for (int off = 1; off < 16; off <<= 1)
#pragma unroll
        for (int r = 0; r < 4; r++)
            rs[r] += __shfl_xor(rs[r], off, 16);
#pragma unroll
    for (int r = 0; r < 4; r++) l_i[r] = l_i[r] * alpha[r] + rs[r];
#pragma unroll
    for (int n = 0; n < 4; n++)
#pragma unroll
        for (int r = 0; r < 4; r++) Oacc[n][r] *= alpha[r];

    // PV: A-frags from LDS (b128), B-frags = V^T rows (contiguous keys)
    constexpr int KC = NT / 2;
    bf16x8 pa[KC];
#pragma unroll
    for (int kc = 0; kc < KC; kc++)
        pa[kc] = *(const bf16x8*)(P + col * kPSTR + kc * 32 + quad * 8);
#pragma unroll
    for (int n = 0; n < 4; n++) {
        const bf16* vr = vbase + (size_t)(16 * n + col) * kSP + s0 + quad * 8;
#pragma unroll
        for (int kc = 0; kc < KC; kc++) {
            const bf16x8 vf = *(const bf16x8*)(vr + kc * 32);
            Oacc[n] = __builtin_amdgcn_mfma_f32_16x16x32_bf16(pa[kc], vf, Oacc[n], 0, 0, 0);
        }
    }
}

__global__ __launch_bounds__(256) void fattn_kernel(const bf16* __restrict__ q_ws,
                                                    const bf16* __restrict__ k_ws,
                                                    const bf16* __restrict__ vt_ws,
                                                    bf16* __restrict__ ctx) {
    __shared__ bf16 Pbuf[4][16 * kPSTR];

    const int qb = blockIdx.x;          // 0..23
    const int bh = blockIdx.y;          // 0..95
    const int b  = bh / kH;
    const int h  = bh - b * kH;
    const int tid  = threadIdx.x;
    const int w    = tid >> 6;
    const int lane = tid & 63;
    const int col  = lane & 15;
    const int quad = lane >> 4;
    const int q0   = qb * 64 + w * 16;  // this wave's 16 Q rows
    if (q0 >= kS) return;               // waves fully past the valid rows

    const bf16* qbase = q_ws  + (size_t)bh * kSP * kDH;
    const bf16* kbase = k_ws  + (size_t)bh * kSP * kDH;
    const bf16* vbase = vt_ws + (size_t)bh * kDH * kSP;

    bf16x8 qf[2];
    qf[0] = *(const bf16x8*)(qbase + (size_t)(q0 + col) * kDH + quad * 8);
    qf[1] = *(const bf16x8*)(qbase + (size_t)(q0 + col) * kDH + 32 + quad * 8);

    float m_i[4], l_i[4];
    floatx4 Oacc[4];
#pragma unroll
    for (int r = 0; r < 4; r++) { m_i[r] = -1e30f; l_i[r] = 0.f; }
#pragma unroll
    for (int n = 0; n < 4; n++) Oacc[n] = (floatx4){0.f, 0.f, 0.f, 0.f};

    bf16* P = &Pbuf[w][0];

    // 23 full 64-key chunks (keys 0..1471), then 32-key masked tail (1472..1503)
    for (int s0 = 0; s0 < 1472; s0 += 64)
        attn_chunk<4, false>(s0, kbase, vbase, P, qf, m_i, l_i, Oacc, col, quad);
    attn_chunk<2, true>(1472, kbase, vbase, P, qf, m_i, l_i, Oacc, col, quad);

    float rinv[4];
#pragma unroll
    for (int r = 0; r < 4; r++) rinv[r] = 1.0f / l_i[r];
#pragma unroll
    for (int n = 0; n < 4; n++)
#pragma unroll
        for (int r = 0; r < 4; r++) {
            const int q = q0 + quad * 4 + r;
            if (q < kS)
                ctx[((size_t)(b * kS + q)) * kD + h * kDH + 16 * n + col] =
                    (bf16)(Oacc[n][r] * rinv[r]);
        }
}

// ---------------------------------------------------------------------------
extern "C" void kernel_launch(void* const* d_in, const int* in_sizes, int n_in,
                              void* d_out, int out_size, void* d_ws, size_t ws_size,
                              hipStream_t stream) {
    float* out_f = (float*)d_out;   // reference output dtype is float32

    constexpr size_t nX = (size_t)kM * kD;
    constexpr size_t nW = (size_t)kD * kD;
    constexpr size_t per_qkv = (size_t)kB * kH * kSP * kDH;

    bf16* xb    = (bf16*)d_ws;
    bf16* Wqb   = xb + nX;
    bf16* Wkb   = Wqb + nW;
    bf16* Wvb   = Wkb + nW;
    bf16* Wob   = Wvb + nW;
    bf16* q_ws  = Wob + nW;
    bf16* k_ws  = q_ws + per_qkv;
    bf16* vt_ws = k_ws + per_qkv;
    float* bqf  = (float*)(vt_ws + per_qkv);
    float* bvf  = bqf + kD;
    float* bof  = bvf + kD;
    int*  flag  = (int*)(bof + kD);
    bf16* ctx   = xb;   // alias: xb last read by proj<2>, ctx written after

    // 1) dtype probe + input normalization to bf16 (biases to f32)
    detect_kernel<<<1, 256, 0, stream>>>(d_in[0], flag);
    cvt_bf16_kernel<<<(int)((nX + 255) / 256), 256, 0, stream>>>(d_in[0], xb,  (int)nX, flag);
    cvt_bf16_kernel<<<(int)((nW + 255) / 256), 256, 0, stream>>>(d_in[1], Wqb, (int)nW, flag);
    cvt_bf16_kernel<<<(int)((nW + 255) / 256), 256, 0, stream>>>(d_in[3], Wkb, (int)nW, flag);
    cvt_bf16_kernel<<<(int)((nW + 255) / 256), 256, 0, stream>>>(d_in[4], Wvb, (int)nW, flag);
    cvt_bf16_kernel<<<(int)((nW + 255) / 256), 256, 0, stream>>>(d_in[6], Wob, (int)nW, flag);
    cvt_f32_kernel<<<3, 256, 0, stream>>>(d_in[2], bqf, kD, flag);
    cvt_f32_kernel<<<3, 256, 0, stream>>>(d_in[5], bvf, kD, flag);
    cvt_f32_kernel<<<3, 256, 0, stream>>>(d_in[7], bof, kD, flag);

    // 2) QKV projections (+ padding)
    zeropad_kernel<<<96, 256, 0, stream>>>(q_ws, k_ws, vt_ws);
    dim3 pgrid((kM + 63) / 64, kD / 64);   // 188 x 12
    proj_kernel<0><<<pgrid, 256, 0, stream>>>(xb, Wqb, bqf, q_ws, nullptr);
    proj_kernel<1><<<pgrid, 256, 0, stream>>>(xb, Wkb, nullptr, k_ws, nullptr);
    proj_kernel<2><<<pgrid, 256, 0, stream>>>(xb, Wvb, bvf, vt_ws, nullptr);

    // 3) flash attention (grid: 24 Q-blocks x 96 bh)
    fattn_kernel<<<dim3(24, kB * kH), 256, 0, stream>>>(q_ws, k_ws, vt_ws, ctx);

    // 4) output projection -> float32 d_out
    proj_kernel<3><<<pgrid, 256, 0, stream>>>(ctx, Wob, bof, nullptr, out_f);
}